// Round 1
// baseline (39790.961 us; speedup 1.0000x reference)
//
#include <hip/hip_runtime.h>
#include <hip/hip_bf16.h>

#define SS 4096
#define TT 2048

// ---------- helpers ----------

__device__ __forceinline__ unsigned short f2bf_rn(float f) {
  unsigned int u = __float_as_uint(f);
  u += 0x7FFFu + ((u >> 16) & 1u);   // round-to-nearest-even; inputs are positive finite
  return (unsigned short)(u >> 16);
}

__device__ __forceinline__ float dot8(uint4 u, float4 qa, float4 qb, float acc) {
  acc = fmaf(__uint_as_float(u.x << 16),          qa.x, acc);
  acc = fmaf(__uint_as_float(u.x & 0xFFFF0000u),  qa.y, acc);
  acc = fmaf(__uint_as_float(u.y << 16),          qa.z, acc);
  acc = fmaf(__uint_as_float(u.y & 0xFFFF0000u),  qa.w, acc);
  acc = fmaf(__uint_as_float(u.z << 16),          qb.x, acc);
  acc = fmaf(__uint_as_float(u.z & 0xFFFF0000u),  qb.y, acc);
  acc = fmaf(__uint_as_float(u.w << 16),          qb.z, acc);
  acc = fmaf(__uint_as_float(u.w & 0xFFFF0000u),  qb.w, acc);
  return acc;
}

// ---------- kernel A: E = bf16(exp(log_trans)) ----------
__global__ void prep_E(const float* __restrict__ lt, unsigned short* __restrict__ E) {
  size_t base = ((size_t)blockIdx.x * 256 + threadIdx.x) * 8;
  float4 a = ((const float4*)(lt + base))[0];
  float4 b = ((const float4*)(lt + base))[1];
  uint4 o;
  o.x = (unsigned)f2bf_rn(__expf(a.x)) | ((unsigned)f2bf_rn(__expf(a.y)) << 16);
  o.y = (unsigned)f2bf_rn(__expf(a.z)) | ((unsigned)f2bf_rn(__expf(a.w)) << 16);
  o.z = (unsigned)f2bf_rn(__expf(b.x)) | ((unsigned)f2bf_rn(__expf(b.y)) << 16);
  o.w = (unsigned)f2bf_rn(__expf(b.z)) | ((unsigned)f2bf_rn(__expf(b.w)) << 16);
  ((uint4*)(E + base))[0] = o;
}

// ---------- kernel B: q0 = exp(log_M0 + log_emit[0]); init flags ----------
__global__ void init_q(const float* __restrict__ m0, const float* __restrict__ emit,
                       float* __restrict__ q, int* __restrict__ prog) {
  int i = blockIdx.x * 256 + threadIdx.x;
  q[i] = __expf(m0[i] + emit[i]);
  if (blockIdx.x == 0) prog[threadIdx.x] = 0;
}

// ---------- kernel C: persistent forward recursion ----------
// 256 blocks x 256 threads, block b owns rows [16b, 16b+16). Flag-based sync:
// prog[b] = last step whose q-chunk block b has published (via LLC atomics).
__global__ void __launch_bounds__(256)
hmm_fwd(const unsigned short* __restrict__ E, const float* __restrict__ emit,
        float* q, int* prog, float* out) {
  __shared__ float qs[SS];
  __shared__ float wsum[4];
  const int b    = blockIdx.x;
  const int tid  = threadIdx.x;
  const int wave = tid >> 6;
  const int lane = tid & 63;
  const int row0 = (b << 4) + (wave << 2);

  const uint4* e0 = (const uint4*)(E + (size_t)(row0 + 0) * SS);
  const uint4* e1 = (const uint4*)(E + (size_t)(row0 + 1) * SS);
  const uint4* e2 = (const uint4*)(E + (size_t)(row0 + 2) * SS);
  const uint4* e3 = (const uint4*)(E + (size_t)(row0 + 3) * SS);

  for (int t = 1; t <= TT; ++t) {
    // wait until every block has published step t-1 (relaxed: no L2-invalidating acquire)
    while (__hip_atomic_load(&prog[tid], __ATOMIC_RELAXED, __HIP_MEMORY_SCOPE_AGENT) < t - 1)
      __builtin_amdgcn_s_sleep(1);

    // stage q_{t-1} (LLC-direct loads -> LDS)
    float* qsrc = q + ((t - 1) & 1) * SS;
#pragma unroll
    for (int k = 0; k < 16; ++k) {
      int idx = tid + (k << 8);
      qs[idx] = __hip_atomic_load(&qsrc[idx], __ATOMIC_RELAXED, __HIP_MEMORY_SCOPE_AGENT);
    }
    __syncthreads();

    // GEMV: 4 rows per wave, 64 cols per lane per row
    float acc0 = 0.f, acc1 = 0.f, acc2 = 0.f, acc3 = 0.f;
    for (int k = 0; k < 8; ++k) {
      int vi = (k << 6) + lane;                       // uint4 index into row
      const float4* qp = (const float4*)(qs + (k << 9) + (lane << 3));
      float4 qa = qp[0], qb = qp[1];
      acc0 = dot8(e0[vi], qa, qb, acc0);
      acc1 = dot8(e1[vi], qa, qb, acc1);
      acc2 = dot8(e2[vi], qa, qb, acc2);
      acc3 = dot8(e3[vi], qa, qb, acc3);
    }
#pragma unroll
    for (int m = 32; m > 0; m >>= 1) {
      acc0 += __shfl_xor(acc0, m);
      acc1 += __shfl_xor(acc1, m);
      acc2 += __shfl_xor(acc2, m);
      acc3 += __shfl_xor(acc3, m);
    }

    // publish q_t chunk (write-through LLC atomics), then release-fence (writeback only)
    float* qdst = q + (t & 1) * SS;
    if (lane == 0) {
      const float* em = emit + (size_t)t * SS + row0;
      float scale = ((t & 255) == 0) ? 0x1p-46f : 1.0f;   // exact pow2 renorm, 8x total
      __hip_atomic_store(&qdst[row0 + 0], acc0 * (__expf(em[0]) * scale),
                         __ATOMIC_RELAXED, __HIP_MEMORY_SCOPE_AGENT);
      __hip_atomic_store(&qdst[row0 + 1], acc1 * (__expf(em[1]) * scale),
                         __ATOMIC_RELAXED, __HIP_MEMORY_SCOPE_AGENT);
      __hip_atomic_store(&qdst[row0 + 2], acc2 * (__expf(em[2]) * scale),
                         __ATOMIC_RELAXED, __HIP_MEMORY_SCOPE_AGENT);
      __hip_atomic_store(&qdst[row0 + 3], acc3 * (__expf(em[3]) * scale),
                         __ATOMIC_RELAXED, __HIP_MEMORY_SCOPE_AGENT);
      __builtin_amdgcn_fence(__ATOMIC_RELEASE, "agent");  // drain stores; no cache invalidate
    }
    __syncthreads();                                       // all waves' q stores drained
    if (tid == 0)
      __hip_atomic_store(&prog[b], t, __ATOMIC_RELAXED, __HIP_MEMORY_SCOPE_AGENT);
  }

  // final reduction: lik = log(sum q_T) + 8*46*ln2
  if (b == 0) {
    while (__hip_atomic_load(&prog[tid], __ATOMIC_RELAXED, __HIP_MEMORY_SCOPE_AGENT) < TT)
      __builtin_amdgcn_s_sleep(1);
    float s = 0.f;
    float* qf = q;                                         // TT even -> buffer 0
#pragma unroll
    for (int k = 0; k < 16; ++k)
      s += __hip_atomic_load(&qf[tid + (k << 8)], __ATOMIC_RELAXED, __HIP_MEMORY_SCOPE_AGENT);
#pragma unroll
    for (int m = 32; m > 0; m >>= 1) s += __shfl_xor(s, m);
    if (lane == 0) wsum[wave] = s;
    __syncthreads();
    if (tid == 0) {
      float tot = wsum[0] + wsum[1] + wsum[2] + wsum[3];
      out[0] = logf(tot) + 368.0f * 0.693147180559945f;    // 8 rescales * 46 * ln2
    }
  }
}

// ---------- launch ----------
extern "C" void kernel_launch(void* const* d_in, const int* in_sizes, int n_in,
                              void* d_out, int out_size, void* d_ws, size_t ws_size,
                              hipStream_t stream) {
  const float* log_M0   = (const float*)d_in[0];
  const float* log_trans= (const float*)d_in[1];
  const float* log_emit = (const float*)d_in[2];
  // d_in[3] = T (fixed 2048, unused)

  unsigned short* E = (unsigned short*)d_ws;                       // 32 MiB bf16
  float* q  = (float*)((char*)d_ws + (size_t)SS * SS * 2);         // 2 x 16 KiB
  int* prog = (int*)((char*)d_ws + (size_t)SS * SS * 2 + 2 * SS * 4); // 1 KiB
  float* out = (float*)d_out;

  hipLaunchKernelGGL(prep_E, dim3((SS * SS) / 2048), dim3(256), 0, stream, log_trans, E);
  hipLaunchKernelGGL(init_q, dim3(SS / 256), dim3(256), 0, stream, log_M0, log_emit, q, prog);
  hipLaunchKernelGGL(hmm_fwd, dim3(256), dim3(256), 0, stream, E, log_emit, q, prog, out);
}